// Round 12
// baseline (113.346 us; speedup 1.0000x reference)
//
#include <hip/hip_runtime.h>

// Problem constants: B=8, C=128, L=2048, H=4, D=32
#define Bsz 8
#define Cdim 128
#define Lseq 2048
#define NH 4
#define HD 32
#define BH 32
// 1/sqrt(D) * log2(e): scores feed v_exp_f32 (2^x) directly
#define QSCALE (0.17677669529663687f * 1.4426950408889634f)

typedef __bf16 bf16x8 __attribute__((ext_vector_type(8)));
typedef float f32x4 __attribute__((ext_vector_type(4)));
typedef unsigned u32x4 __attribute__((ext_vector_type(4)));

__device__ __forceinline__ float fexp2(float x) {
#if __has_builtin(__builtin_amdgcn_exp2f)
    return __builtin_amdgcn_exp2f(x);
#else
    return __expf(x * 0.6931471805599453f);
#endif
}

__device__ __forceinline__ unsigned short f2bf(float f) {   // RNE
    unsigned u = __builtin_bit_cast(unsigned, f);
    u += 0x7FFFu + ((u >> 16) & 1u);
    return (unsigned short)(u >> 16);
}

__device__ __forceinline__ unsigned pack_bf16(float a, float b) {  // RNE pair
    return (unsigned)f2bf(a) | ((unsigned)f2bf(b) << 16);
}

// RTZ pack of two f32 -> packed bf16x2, single v_perm_b32.
__device__ __forceinline__ unsigned pack_bf16_rtz(float a, float b) {
    return __builtin_amdgcn_perm(__builtin_bit_cast(unsigned, b),
                                 __builtin_bit_cast(unsigned, a), 0x07060302u);
}

__device__ __forceinline__ float bf_lo(unsigned u) {
    return __builtin_bit_cast(float, u << 16);
}
__device__ __forceinline__ float bf_hi(unsigned u) {
    return __builtin_bit_cast(float, u & 0xFFFF0000u);
}

#define MFMA16(A, B, C) __builtin_amdgcn_mfma_f32_16x16x32_bf16((A), (B), (C), 0, 0, 0)

// ---------------------------------------------------------------------------
// Kernel 1: QKV projection — og-merged, XCD-colocated trios. Grid 768.
// bid swizzle: the 3 og3 blocks sharing one (b,lt) x-tile land on the SAME
// XCD (bid%8) -> x-tile HBM-fetched once per trio.
// V epilogue: acc -> LDS tile V2[kk][o] (vector u32 ds_writes), barrier,
// kappa-GATHER from LDS, store dwordx4 (4 coalesced 4KB region writes).
// Q,K -> [bh][l][32]; V -> kappa-permuted tile [bh][kc64][d32][pos64].
// (R4-verified configuration)
// ---------------------------------------------------------------------------
__global__ __launch_bounds__(256) void qkv_kernel(const float* __restrict__ x,
        const float* __restrict__ w, const float* __restrict__ bias,
        unsigned short* __restrict__ qh, unsigned short* __restrict__ kh,
        unsigned short* __restrict__ vh) {
    __shared__ __attribute__((aligned(16))) unsigned short T[64][132];
    __shared__ __attribute__((aligned(16))) unsigned short V2[64][132];
    int bid = blockIdx.x;
    int xcd = bid & 7;
    int s   = bid >> 3;               // 0..95
    int og3 = s % 3;                  // 0=Q, 1=K, 2=V (128 o each)
    int u_  = s / 3;                  // 0..31
    int trio = u_ * 8 + xcd;          // 0..255
    int lt  = trio & 31;              // 32 l-tiles of 64
    int b   = trio >> 5;
    int l0 = lt * 64;
    int t = threadIdx.x;
    int lane = t & 63, wv = t >> 6;
    int m16 = lane & 15, quad = lane >> 4;

    // A-frags for 2 o-subtiles (wv*16 and 64+wv*16 within this og3 group)
    bf16x8 af[2][4];
    float bs[2][4];
    #pragma unroll
    for (int os = 0; os < 2; os++) {
        int orow = og3 * 128 + os * 64 + wv * 16;
        #pragma unroll
        for (int ks = 0; ks < 4; ks++) {
            const float* p = w + (size_t)(orow + m16) * Cdim + ks * 32 + quad * 8;
            float4 f0 = *(const float4*)p;
            float4 f1 = *(const float4*)(p + 4);
            u32x4 u = {pack_bf16(f0.x, f0.y), pack_bf16(f0.z, f0.w),
                       pack_bf16(f1.x, f1.y), pack_bf16(f1.z, f1.w)};
            af[os][ks] = __builtin_bit_cast(bf16x8, u);
        }
        #pragma unroll
        for (int r = 0; r < 4; r++) bs[os][r] = bias[orow + quad * 4 + r];
    }

    // stage x tile: T[l][c] = bf16(x[b][c][l0+l]); coalesced over l
    {
        int ll = t & 63, cg = t >> 6;
        const float* xb = x + (size_t)b * Cdim * Lseq + l0 + ll;
        #pragma unroll
        for (int i = 0; i < 16; i++) {
            int c = cg * 32 + 2 * i;
            float f0 = xb[(size_t)c * Lseq];
            float f1 = xb[(size_t)(c + 1) * Lseq];
            *(unsigned*)&T[ll][c] = pack_bf16(f0, f1);
        }
    }
    __syncthreads();

    #pragma unroll
    for (int ns = 0; ns < 4; ns++) {
        bf16x8 bx[4];   // B[k=c][n=l(m16)] — shared by both o-subtiles
        #pragma unroll
        for (int ks = 0; ks < 4; ks++)
            bx[ks] = *(const bf16x8*)(&T[ns * 16 + m16][ks * 32 + quad * 8]);
        int l = l0 + ns * 16 + m16;
        #pragma unroll
        for (int os = 0; os < 2; os++) {
            f32x4 acc = {0.f, 0.f, 0.f, 0.f};
            #pragma unroll
            for (int ks = 0; ks < 4; ks++) acc = MFMA16(af[os][ks], bx[ks], acc);
            int oq = os * 64 + wv * 16 + quad * 4;   // o within the 128-group
            if (og3 == 0) {          // Q (scaled)
                int h = oq >> 5, d0 = oq & 31;
                uint2 u;
                u.x = pack_bf16((acc[0] + bs[os][0]) * QSCALE, (acc[1] + bs[os][1]) * QSCALE);
                u.y = pack_bf16((acc[2] + bs[os][2]) * QSCALE, (acc[3] + bs[os][3]) * QSCALE);
                *(uint2*)(qh + ((size_t)(b * NH + h) * Lseq + l) * HD + d0) = u;
            } else if (og3 == 1) {   // K
                int h = oq >> 5, d0 = oq & 31;
                uint2 u;
                u.x = pack_bf16(acc[0] + bs[os][0], acc[1] + bs[os][1]);
                u.y = pack_bf16(acc[2] + bs[os][2], acc[3] + bs[os][3]);
                *(uint2*)(kh + ((size_t)(b * NH + h) * Lseq + l) * HD + d0) = u;
            } else {                 // V -> LDS tile [kk][o], vectorized
                int kk = l & 63;
                uint2 u;
                u.x = pack_bf16(acc[0] + bs[os][0], acc[1] + bs[os][1]);
                u.y = pack_bf16(acc[2] + bs[os][2], acc[3] + bs[os][3]);
                *(uint2*)&V2[kk][oq] = u;
            }
        }
    }

    if (og3 == 2) {
        // kappa-gather from LDS -> coalesced dwordx4 stores (one 4KB
        // (bh,kc) region per s-iteration). Inverse kappa: pos=half*32+q*8+j,
        // j<4 -> kk=half*32+q*4+j ; j>=4 -> kk=half*32+16+q*4+(j-4).
        __syncthreads();
        int kc = l0 >> 6;
        #pragma unroll
        for (int s2 = 0; s2 < 4; s2++) {
            int i = t + 256 * s2;            // 0..1023
            int o = i >> 3;                  // 0..127
            int pos0 = (i & 7) * 8;          // 8-aligned pos group
            int half = pos0 >> 5, qq = (pos0 & 31) >> 3;
            int kb2 = half * 32 + qq * 4;
            unsigned short e0 = V2[kb2 + 0][o], e1 = V2[kb2 + 1][o];
            unsigned short e2 = V2[kb2 + 2][o], e3 = V2[kb2 + 3][o];
            unsigned short e4 = V2[kb2 + 16][o], e5 = V2[kb2 + 17][o];
            unsigned short e6 = V2[kb2 + 18][o], e7 = V2[kb2 + 19][o];
            uint4 u;
            u.x = (unsigned)e0 | ((unsigned)e1 << 16);
            u.y = (unsigned)e2 | ((unsigned)e3 << 16);
            u.z = (unsigned)e4 | ((unsigned)e5 << 16);
            u.w = (unsigned)e6 | ((unsigned)e7 << 16);
            int h = o >> 5, d = o & 31;
            *(uint4*)(vh + (((size_t)(b * NH + h) * 32 + kc) * HD + d) * 64 + pos0) = u;
        }
    }
}

// ---------------------------------------------------------------------------
// Kernel 2: MFMA flash attention — 64-q blocks with the R4-PROVEN chunk
// structure. Grid 1024 (xcd, qt32, g4); wave = 64 q x 512 keys, 8 chunks of
// 64 keys, kf[4]/vf[4] A/B double-buffer, STRAIGHT-LINE schedule (no unrolled
// loop — R9's 32-key unrolled loop ballooned natural allocation to 256 VGPR).
// NO waves-hint (R7/R8: forced hints split the unified file and spill).
// This is a strict register-subset of the verified R4 kernel (qf 32->16,
// oacc 64->32, sacc 8->4): natural allocation ~100-130 -> 4 waves/SIMD, and
// grid 1024 x 4 waves = 4096 = one full round at 4/SIMD (2x R4's TLP).
// Rowsum = VALU add-tree. Normalize in-kernel; write bf16 o[bh][l][d].
// ---------------------------------------------------------------------------
__global__ __launch_bounds__(256) void attn_kernel(
        const unsigned short* __restrict__ qh, const unsigned short* __restrict__ kh,
        const unsigned short* __restrict__ vh, unsigned short* __restrict__ oo) {
    // red_o: [4 waves][64 rows][20 uints] = 20480 B; red_l: [4][64][4] f32 @20480
    __shared__ __attribute__((aligned(16))) char smem[24576];

    int bid = blockIdx.x;
    int xcd  = bid & 7;                 // same bh -> same XCD (K/V L2 residency)
    int rest = bid >> 3;
    int qt = rest & 31;                 // 32 tiles of 64 q
    int g  = rest >> 5;                 // 0..3
    int bh = xcd + 8 * g;

    int lane = threadIdx.x & 63;
    int wv   = threadIdx.x >> 6;
    int m16  = lane & 15;
    int quad = lane >> 4;
    int l0 = qt * 64;

    bf16x8 qf[4];
    #pragma unroll
    for (int qs = 0; qs < 4; qs++)
        qf[qs] = *(const bf16x8*)(
            qh + ((size_t)bh * Lseq + l0 + qs * 16 + m16) * HD + quad * 8);

    f32x4 oacc[4][2];
    float sacc[4];
    #pragma unroll
    for (int qs = 0; qs < 4; qs++) {
        oacc[qs][0] = f32x4{0.f, 0.f, 0.f, 0.f};
        oacc[qs][1] = f32x4{0.f, 0.f, 0.f, 0.f};
        sacc[qs]    = 0.f;
    }
    f32x4 zero = {0.f, 0.f, 0.f, 0.f};

    const unsigned short* kb = kh + (size_t)bh * Lseq * HD + m16 * HD + quad * 8;
    const unsigned short* vb = vh + (size_t)bh * 32 * HD * 64;
    int kbase = wv * 512;               // wave owns 512 keys, 8 chunks of 64

    auto load_kv = [&](int chunk, bf16x8* kf, bf16x8* vf) {
        int k0 = kbase + chunk * 64;
        #pragma unroll
        for (int t = 0; t < 4; t++)
            kf[t] = *(const bf16x8*)(kb + (size_t)(k0 + 16 * t) * HD);
        const unsigned short* vch = vb + (size_t)(k0 >> 6) * (HD * 64);
        vf[0] = *(const bf16x8*)(vch + m16 * 64 + quad * 8);
        vf[1] = *(const bf16x8*)(vch + (16 + m16) * 64 + quad * 8);
        vf[2] = *(const bf16x8*)(vch + m16 * 64 + 32 + quad * 8);
        vf[3] = *(const bf16x8*)(vch + (16 + m16) * 64 + 32 + quad * 8);
    };

    auto compute = [&](const bf16x8* kf, const bf16x8* vf) {
        #pragma unroll
        for (int qs = 0; qs < 4; qs++) {
            f32x4 s0 = MFMA16(kf[0], qf[qs], zero);
            f32x4 s1 = MFMA16(kf[1], qf[qs], zero);
            f32x4 s2 = MFMA16(kf[2], qf[qs], zero);
            f32x4 s3 = MFMA16(kf[3], qf[qs], zero);
            float p00 = fexp2(s0[0]), p01 = fexp2(s0[1]), p02 = fexp2(s0[2]), p03 = fexp2(s0[3]);
            float p10 = fexp2(s1[0]), p11 = fexp2(s1[1]), p12 = fexp2(s1[2]), p13 = fexp2(s1[3]);
            float p20 = fexp2(s2[0]), p21 = fexp2(s2[1]), p22 = fexp2(s2[2]), p23 = fexp2(s2[3]);
            float p30 = fexp2(s3[0]), p31 = fexp2(s3[1]), p32 = fexp2(s3[2]), p33 = fexp2(s3[3]);
            // per-lane rowsum partial (this lane's 16 of 64 keys) on the VALU
            float r0 = (p00 + p01) + (p02 + p03);
            float r1 = (p10 + p11) + (p12 + p13);
            float r2 = (p20 + p21) + (p22 + p23);
            float r3 = (p30 + p31) + (p32 + p33);
            sacc[qs] += (r0 + r1) + (r2 + r3);
            // packed regs ARE the P B-frag in kappa key-order
            u32x4 lo = {pack_bf16_rtz(p00, p01), pack_bf16_rtz(p02, p03),
                        pack_bf16_rtz(p10, p11), pack_bf16_rtz(p12, p13)};
            u32x4 hi = {pack_bf16_rtz(p20, p21), pack_bf16_rtz(p22, p23),
                        pack_bf16_rtz(p30, p31), pack_bf16_rtz(p32, p33)};
            bf16x8 pfL = __builtin_bit_cast(bf16x8, lo);
            bf16x8 pfH = __builtin_bit_cast(bf16x8, hi);
            oacc[qs][0] = MFMA16(vf[0], pfL, oacc[qs][0]);
            oacc[qs][1] = MFMA16(vf[1], pfL, oacc[qs][1]);
            oacc[qs][0] = MFMA16(vf[2], pfH, oacc[qs][0]);
            oacc[qs][1] = MFMA16(vf[3], pfH, oacc[qs][1]);
        }
    };

    bf16x8 kA[4], vA[4], kB[4], vB[4];
    load_kv(0, kA, vA);
    load_kv(1, kB, vB);
    compute(kA, vA); load_kv(2, kA, vA);
    compute(kB, vB); load_kv(3, kB, vB);
    compute(kA, vA); load_kv(4, kA, vA);
    compute(kB, vB); load_kv(5, kB, vB);
    compute(kA, vA); load_kv(6, kA, vA);
    compute(kB, vB); load_kv(7, kB, vB);
    compute(kA, vA);
    compute(kB, vB);

    // cross-wave reduction: packed-bf16 partials + per-lane rowsum partials,
    // one barrier; then normalize (full rowsum known) and write bf16 o.
    unsigned* red_o = (unsigned*)smem;               // [4][64 rows][20]
    float* red_l = (float*)(smem + 20480);           // [4][64 rows][4 quads]
    #pragma unroll
    for (int qs = 0; qs < 4; qs++) {
        int row = qs * 16 + m16;
        unsigned* rw = red_o + (size_t)(wv * 64 + row) * 20;
        *(uint2*)(rw + 2 * quad) =
            make_uint2(pack_bf16_rtz(oacc[qs][0][0], oacc[qs][0][1]),
                       pack_bf16_rtz(oacc[qs][0][2], oacc[qs][0][3]));
        *(uint2*)(rw + 8 + 2 * quad) =
            make_uint2(pack_bf16_rtz(oacc[qs][1][0], oacc[qs][1][1]),
                       pack_bf16_rtz(oacc[qs][1][2], oacc[qs][1][3]));
        red_l[(wv * 64 + row) * 4 + quad] = sacc[qs];
    }
    __syncthreads();

    // combine 4 waves -> normalized bf16 o[bh][l][d]; 4 threads per q-row
    int q = threadIdx.x >> 2;           // 0..63
    int s4 = (threadIdx.x & 3) * 4;
    float a8[8] = {0.f, 0.f, 0.f, 0.f, 0.f, 0.f, 0.f, 0.f};
    float ltot = 0.f;
    #pragma unroll
    for (int w = 0; w < 4; w++) {
        const unsigned* rr = red_o + (size_t)(w * 64 + q) * 20 + s4;
        uint2 ua = *(const uint2*)(rr);
        uint2 ub = *(const uint2*)(rr + 2);
        a8[0] += bf_lo(ua.x); a8[1] += bf_hi(ua.x);
        a8[2] += bf_lo(ua.y); a8[3] += bf_hi(ua.y);
        a8[4] += bf_lo(ub.x); a8[5] += bf_hi(ub.x);
        a8[6] += bf_lo(ub.y); a8[7] += bf_hi(ub.y);
        float4 lv = *(const float4*)(red_l + (size_t)(w * 64 + q) * 4);
        ltot += (lv.x + lv.y) + (lv.z + lv.w);
    }
    float inv = 1.0f / ltot;
    int d0 = (threadIdx.x & 3) * 8;
    uint4 u;
    u.x = pack_bf16(a8[0] * inv, a8[1] * inv);
    u.y = pack_bf16(a8[2] * inv, a8[3] * inv);
    u.z = pack_bf16(a8[4] * inv, a8[5] * inv);
    u.w = pack_bf16(a8[6] * inv, a8[7] * inv);
    *(uint4*)(oo + ((size_t)bh * Lseq + l0 + q) * HD + d0) = u;
}

// ---------------------------------------------------------------------------
// Kernel 3: projection + bias + residual. o is normalized bf16 in [bh][l][d];
// B-frag loaded directly from global (L2-resident, full-line coalesced).
// Grid 1024: block = 64 o x 32 n. (R4-verified)
// ---------------------------------------------------------------------------
__global__ __launch_bounds__(256) void proj_kernel(const float* __restrict__ wp,
        const unsigned short* __restrict__ oo, const float* __restrict__ bias,
        const float* __restrict__ x, float* __restrict__ out) {
    int bid = blockIdx.x;
    int ot = bid & 1;
    int nt = bid >> 1;                // 0..511, 32-n tiles
    int n0 = nt * 32;
    int t = threadIdx.x;
    int lane = t & 63;
    int wv = t >> 6;
    int m16 = lane & 15, quad = lane >> 4;
    int o0 = ot * 64 + wv * 16;

    bf16x8 af[4];
    #pragma unroll
    for (int ks = 0; ks < 4; ks++) {
        const float* p = wp + (size_t)(o0 + m16) * Cdim + ks * 32 + quad * 8;
        float4 f0 = *(const float4*)p;
        float4 f1 = *(const float4*)(p + 4);
        u32x4 u = {pack_bf16(f0.x, f0.y), pack_bf16(f0.z, f0.w),
                   pack_bf16(f1.x, f1.y), pack_bf16(f1.z, f1.w)};
        af[ks] = __builtin_bit_cast(bf16x8, u);
    }
    float bs[4];
    #pragma unroll
    for (int r = 0; r < 4; r++) bs[r] = bias[o0 + quad * 4 + r];
    int oq = o0 + quad * 4;

    #pragma unroll
    for (int lt2 = 0; lt2 < 2; lt2++) {
        int n = n0 + lt2 * 16 + m16;
        int b = n >> 11, l = n & (Lseq - 1);
        // B-frag straight from global: c = ks*32 + quad*8 + j  ->  h=ks, d=quad*8+j
        bf16x8 bx[4];
        #pragma unroll
        for (int ks = 0; ks < 4; ks++)
            bx[ks] = *(const bf16x8*)(oo + ((size_t)(b * NH + ks) * Lseq + l) * HD + quad * 8);
        f32x4 acc = {0.f, 0.f, 0.f, 0.f};
        #pragma unroll
        for (int ks = 0; ks < 4; ks++) acc = MFMA16(af[ks], bx[ks], acc);
        #pragma unroll
        for (int r = 0; r < 4; r++) {
            size_t xi = ((size_t)b * Cdim + oq + r) * Lseq + l;
            out[xi] = acc[r] + bs[r] + x[xi];
        }
    }
}

extern "C" void kernel_launch(void* const* d_in, const int* in_sizes, int n_in,
                              void* d_out, int out_size, void* d_ws, size_t ws_size,
                              hipStream_t stream) {
    const float* x      = (const float*)d_in[0];
    const float* w_qkv  = (const float*)d_in[1];
    const float* b_qkv  = (const float*)d_in[2];
    const float* w_proj = (const float*)d_in[3];
    const float* b_proj = (const float*)d_in[4];
    float* out = (float*)d_out;

    // ws: qh 4MB | kh 4MB | vh 4MB | oo 4MB bf16 [BH][L][HD] (normalized)
    const size_t E = (size_t)BH * Lseq * HD;   // 2M elems
    unsigned short* qh = (unsigned short*)d_ws;
    unsigned short* kh = qh + E;
    unsigned short* vh = kh + E;
    unsigned short* oo = vh + E;               // [BH][Lseq][HD] bf16, normalized

    qkv_kernel<<<dim3(768), dim3(256), 0, stream>>>(x, w_qkv, b_qkv, qh, kh, vh);
    attn_kernel<<<dim3(1024), dim3(256), 0, stream>>>(qh, kh, vh, oo);
    proj_kernel<<<dim3(1024), dim3(256), 0, stream>>>(w_proj, oo, b_proj, x, out);
}

// Round 13
// 107.542 us; speedup vs baseline: 1.0540x; 1.0540x over previous
//
#include <hip/hip_runtime.h>

// Problem constants: B=8, C=128, L=2048, H=4, D=32
#define Bsz 8
#define Cdim 128
#define Lseq 2048
#define NH 4
#define HD 32
#define BH 32
// 1/sqrt(D) * log2(e): scores feed v_exp_f32 (2^x) directly
#define QSCALE (0.17677669529663687f * 1.4426950408889634f)

typedef __bf16 bf16x8 __attribute__((ext_vector_type(8)));
typedef float f32x4 __attribute__((ext_vector_type(4)));
typedef unsigned u32x4 __attribute__((ext_vector_type(4)));

__device__ __forceinline__ float fexp2(float x) {
#if __has_builtin(__builtin_amdgcn_exp2f)
    return __builtin_amdgcn_exp2f(x);
#else
    return __expf(x * 0.6931471805599453f);
#endif
}

__device__ __forceinline__ unsigned short f2bf(float f) {   // RNE
    unsigned u = __builtin_bit_cast(unsigned, f);
    u += 0x7FFFu + ((u >> 16) & 1u);
    return (unsigned short)(u >> 16);
}

__device__ __forceinline__ unsigned pack_bf16(float a, float b) {  // RNE pair
    return (unsigned)f2bf(a) | ((unsigned)f2bf(b) << 16);
}

// RTZ pack of two f32 -> packed bf16x2, single v_perm_b32.
__device__ __forceinline__ unsigned pack_bf16_rtz(float a, float b) {
    return __builtin_amdgcn_perm(__builtin_bit_cast(unsigned, b),
                                 __builtin_bit_cast(unsigned, a), 0x07060302u);
}

__device__ __forceinline__ float bf_lo(unsigned u) {
    return __builtin_bit_cast(float, u << 16);
}
__device__ __forceinline__ float bf_hi(unsigned u) {
    return __builtin_bit_cast(float, u & 0xFFFF0000u);
}

#define MFMA16(A, B, C) __builtin_amdgcn_mfma_f32_16x16x32_bf16((A), (B), (C), 0, 0, 0)

// ---------------------------------------------------------------------------
// Kernel 1: QKV projection — og-merged, XCD-colocated trios. Grid 768.
// bid swizzle: the 3 og3 blocks sharing one (b,lt) x-tile land on the SAME
// XCD (bid%8) -> x-tile HBM-fetched once per trio.
// V epilogue: acc -> LDS tile V2[kk][o] (vector u32 ds_writes), barrier,
// kappa-GATHER from LDS, store dwordx4 (4 coalesced 4KB region writes).
// Q,K -> [bh][l][32]; V -> kappa-permuted tile [bh][kc64][d32][pos64].
// (R4-verified configuration)
// ---------------------------------------------------------------------------
__global__ __launch_bounds__(256) void qkv_kernel(const float* __restrict__ x,
        const float* __restrict__ w, const float* __restrict__ bias,
        unsigned short* __restrict__ qh, unsigned short* __restrict__ kh,
        unsigned short* __restrict__ vh) {
    __shared__ __attribute__((aligned(16))) unsigned short T[64][132];
    __shared__ __attribute__((aligned(16))) unsigned short V2[64][132];
    int bid = blockIdx.x;
    int xcd = bid & 7;
    int s   = bid >> 3;               // 0..95
    int og3 = s % 3;                  // 0=Q, 1=K, 2=V (128 o each)
    int u_  = s / 3;                  // 0..31
    int trio = u_ * 8 + xcd;          // 0..255
    int lt  = trio & 31;              // 32 l-tiles of 64
    int b   = trio >> 5;
    int l0 = lt * 64;
    int t = threadIdx.x;
    int lane = t & 63, wv = t >> 6;
    int m16 = lane & 15, quad = lane >> 4;

    // A-frags for 2 o-subtiles (wv*16 and 64+wv*16 within this og3 group)
    bf16x8 af[2][4];
    float bs[2][4];
    #pragma unroll
    for (int os = 0; os < 2; os++) {
        int orow = og3 * 128 + os * 64 + wv * 16;
        #pragma unroll
        for (int ks = 0; ks < 4; ks++) {
            const float* p = w + (size_t)(orow + m16) * Cdim + ks * 32 + quad * 8;
            float4 f0 = *(const float4*)p;
            float4 f1 = *(const float4*)(p + 4);
            u32x4 u = {pack_bf16(f0.x, f0.y), pack_bf16(f0.z, f0.w),
                       pack_bf16(f1.x, f1.y), pack_bf16(f1.z, f1.w)};
            af[os][ks] = __builtin_bit_cast(bf16x8, u);
        }
        #pragma unroll
        for (int r = 0; r < 4; r++) bs[os][r] = bias[orow + quad * 4 + r];
    }

    // stage x tile: T[l][c] = bf16(x[b][c][l0+l]); coalesced over l
    {
        int ll = t & 63, cg = t >> 6;
        const float* xb = x + (size_t)b * Cdim * Lseq + l0 + ll;
        #pragma unroll
        for (int i = 0; i < 16; i++) {
            int c = cg * 32 + 2 * i;
            float f0 = xb[(size_t)c * Lseq];
            float f1 = xb[(size_t)(c + 1) * Lseq];
            *(unsigned*)&T[ll][c] = pack_bf16(f0, f1);
        }
    }
    __syncthreads();

    #pragma unroll
    for (int ns = 0; ns < 4; ns++) {
        bf16x8 bx[4];   // B[k=c][n=l(m16)] — shared by both o-subtiles
        #pragma unroll
        for (int ks = 0; ks < 4; ks++)
            bx[ks] = *(const bf16x8*)(&T[ns * 16 + m16][ks * 32 + quad * 8]);
        int l = l0 + ns * 16 + m16;
        #pragma unroll
        for (int os = 0; os < 2; os++) {
            f32x4 acc = {0.f, 0.f, 0.f, 0.f};
            #pragma unroll
            for (int ks = 0; ks < 4; ks++) acc = MFMA16(af[os][ks], bx[ks], acc);
            int oq = os * 64 + wv * 16 + quad * 4;   // o within the 128-group
            if (og3 == 0) {          // Q (scaled)
                int h = oq >> 5, d0 = oq & 31;
                uint2 u;
                u.x = pack_bf16((acc[0] + bs[os][0]) * QSCALE, (acc[1] + bs[os][1]) * QSCALE);
                u.y = pack_bf16((acc[2] + bs[os][2]) * QSCALE, (acc[3] + bs[os][3]) * QSCALE);
                *(uint2*)(qh + ((size_t)(b * NH + h) * Lseq + l) * HD + d0) = u;
            } else if (og3 == 1) {   // K
                int h = oq >> 5, d0 = oq & 31;
                uint2 u;
                u.x = pack_bf16(acc[0] + bs[os][0], acc[1] + bs[os][1]);
                u.y = pack_bf16(acc[2] + bs[os][2], acc[3] + bs[os][3]);
                *(uint2*)(kh + ((size_t)(b * NH + h) * Lseq + l) * HD + d0) = u;
            } else {                 // V -> LDS tile [kk][o], vectorized
                int kk = l & 63;
                uint2 u;
                u.x = pack_bf16(acc[0] + bs[os][0], acc[1] + bs[os][1]);
                u.y = pack_bf16(acc[2] + bs[os][2], acc[3] + bs[os][3]);
                *(uint2*)&V2[kk][oq] = u;
            }
        }
    }

    if (og3 == 2) {
        // kappa-gather from LDS -> coalesced dwordx4 stores (one 4KB
        // (bh,kc) region per s-iteration). Inverse kappa: pos=half*32+q*8+j,
        // j<4 -> kk=half*32+q*4+j ; j>=4 -> kk=half*32+16+q*4+(j-4).
        __syncthreads();
        int kc = l0 >> 6;
        #pragma unroll
        for (int s2 = 0; s2 < 4; s2++) {
            int i = t + 256 * s2;            // 0..1023
            int o = i >> 3;                  // 0..127
            int pos0 = (i & 7) * 8;          // 8-aligned pos group
            int half = pos0 >> 5, qq = (pos0 & 31) >> 3;
            int kb2 = half * 32 + qq * 4;
            unsigned short e0 = V2[kb2 + 0][o], e1 = V2[kb2 + 1][o];
            unsigned short e2 = V2[kb2 + 2][o], e3 = V2[kb2 + 3][o];
            unsigned short e4 = V2[kb2 + 16][o], e5 = V2[kb2 + 17][o];
            unsigned short e6 = V2[kb2 + 18][o], e7 = V2[kb2 + 19][o];
            uint4 u;
            u.x = (unsigned)e0 | ((unsigned)e1 << 16);
            u.y = (unsigned)e2 | ((unsigned)e3 << 16);
            u.z = (unsigned)e4 | ((unsigned)e5 << 16);
            u.w = (unsigned)e6 | ((unsigned)e7 << 16);
            int h = o >> 5, d = o & 31;
            *(uint4*)(vh + (((size_t)(b * NH + h) * 32 + kc) * HD + d) * 64 + pos0) = u;
        }
    }
}

// ---------------------------------------------------------------------------
// Kernel 2: MFMA flash attention — 128-q blocks (grid 512 = xcd, qt16, g4).
// R4-verified structure (107.84/107.88us, twice-verified best). The R6-R12
// occupancy arc is closed: 64-q tiles double per-output K/V load issue
// (attn 38->49.5us at identical chunk structure, zero spill, occupancy flat
// at ~19%); forced waves-hints split the unified reg file and scratch-spill.
// 128-q is the local optimum: 2-deep A/B prefetch, qf[2], VALU rowsum
// add-tree, launch_bounds(256,2), zero spill.
// Normalize in-kernel; write normalized bf16 o[bh][l][d].
// ---------------------------------------------------------------------------
__global__ __launch_bounds__(256, 2) void attn_kernel(
        const unsigned short* __restrict__ qh, const unsigned short* __restrict__ kh,
        const unsigned short* __restrict__ vh, unsigned short* __restrict__ oo) {
    // red_o: [4 waves][128 rows][20 uints] = 40960 B; red_l: [4][128][4] @40960
    __shared__ __attribute__((aligned(16))) char smem[49152];

    int bid = blockIdx.x;
    int xcd  = bid & 7;                 // same bh -> same XCD (K/V L2 residency)
    int rest = bid >> 3;
    int qt = rest & 15;                 // 16 tiles of 128 q
    int g  = rest >> 4;                 // 0..3
    int bh = xcd + 8 * g;

    int lane = threadIdx.x & 63;
    int wv   = threadIdx.x >> 6;
    int m16  = lane & 15;
    int quad = lane >> 4;
    int l0 = qt * 128;

    bf16x8 qf[2][4];
    #pragma unroll
    for (int qt2 = 0; qt2 < 2; qt2++)
        #pragma unroll
        for (int qs = 0; qs < 4; qs++)
            qf[qt2][qs] = *(const bf16x8*)(
                qh + ((size_t)bh * Lseq + l0 + qt2 * 64 + qs * 16 + m16) * HD + quad * 8);

    f32x4 oacc[2][4][2];
    float sacc[2][4];
    #pragma unroll
    for (int qt2 = 0; qt2 < 2; qt2++)
        #pragma unroll
        for (int qs = 0; qs < 4; qs++) {
            oacc[qt2][qs][0] = f32x4{0.f, 0.f, 0.f, 0.f};
            oacc[qt2][qs][1] = f32x4{0.f, 0.f, 0.f, 0.f};
            sacc[qt2][qs]    = 0.f;
        }
    f32x4 zero = {0.f, 0.f, 0.f, 0.f};

    const unsigned short* kb = kh + (size_t)bh * Lseq * HD + m16 * HD + quad * 8;
    const unsigned short* vb = vh + (size_t)bh * 32 * HD * 64;
    int kbase = wv * 512;               // wave owns 512 keys, 8 chunks of 64

    auto load_kv = [&](int chunk, bf16x8* kf, bf16x8* vf) {
        int k0 = kbase + chunk * 64;
        #pragma unroll
        for (int t = 0; t < 4; t++)
            kf[t] = *(const bf16x8*)(kb + (size_t)(k0 + 16 * t) * HD);
        const unsigned short* vch = vb + (size_t)(k0 >> 6) * (HD * 64);
        vf[0] = *(const bf16x8*)(vch + m16 * 64 + quad * 8);
        vf[1] = *(const bf16x8*)(vch + (16 + m16) * 64 + quad * 8);
        vf[2] = *(const bf16x8*)(vch + m16 * 64 + 32 + quad * 8);
        vf[3] = *(const bf16x8*)(vch + (16 + m16) * 64 + 32 + quad * 8);
    };

    auto compute = [&](const bf16x8* kf, const bf16x8* vf) {
        #pragma unroll
        for (int qt2 = 0; qt2 < 2; qt2++) {
            #pragma unroll
            for (int qs = 0; qs < 4; qs++) {
                f32x4 s0 = MFMA16(kf[0], qf[qt2][qs], zero);
                f32x4 s1 = MFMA16(kf[1], qf[qt2][qs], zero);
                f32x4 s2 = MFMA16(kf[2], qf[qt2][qs], zero);
                f32x4 s3 = MFMA16(kf[3], qf[qt2][qs], zero);
                float p00 = fexp2(s0[0]), p01 = fexp2(s0[1]), p02 = fexp2(s0[2]), p03 = fexp2(s0[3]);
                float p10 = fexp2(s1[0]), p11 = fexp2(s1[1]), p12 = fexp2(s1[2]), p13 = fexp2(s1[3]);
                float p20 = fexp2(s2[0]), p21 = fexp2(s2[1]), p22 = fexp2(s2[2]), p23 = fexp2(s2[3]);
                float p30 = fexp2(s3[0]), p31 = fexp2(s3[1]), p32 = fexp2(s3[2]), p33 = fexp2(s3[3]);
                // per-lane rowsum partial (this lane's 16 of 64 keys) on the VALU
                float r0 = (p00 + p01) + (p02 + p03);
                float r1 = (p10 + p11) + (p12 + p13);
                float r2 = (p20 + p21) + (p22 + p23);
                float r3 = (p30 + p31) + (p32 + p33);
                sacc[qt2][qs] += (r0 + r1) + (r2 + r3);
                // packed regs ARE the P B-frag in kappa key-order
                u32x4 lo = {pack_bf16_rtz(p00, p01), pack_bf16_rtz(p02, p03),
                            pack_bf16_rtz(p10, p11), pack_bf16_rtz(p12, p13)};
                u32x4 hi = {pack_bf16_rtz(p20, p21), pack_bf16_rtz(p22, p23),
                            pack_bf16_rtz(p30, p31), pack_bf16_rtz(p32, p33)};
                bf16x8 pfL = __builtin_bit_cast(bf16x8, lo);
                bf16x8 pfH = __builtin_bit_cast(bf16x8, hi);
                oacc[qt2][qs][0] = MFMA16(vf[0], pfL, oacc[qt2][qs][0]);
                oacc[qt2][qs][1] = MFMA16(vf[1], pfL, oacc[qt2][qs][1]);
                oacc[qt2][qs][0] = MFMA16(vf[2], pfH, oacc[qt2][qs][0]);
                oacc[qt2][qs][1] = MFMA16(vf[3], pfH, oacc[qt2][qs][1]);
            }
        }
    };

    bf16x8 kA[4], vA[4], kB[4], vB[4];
    load_kv(0, kA, vA);
    load_kv(1, kB, vB);
    compute(kA, vA); load_kv(2, kA, vA);
    compute(kB, vB); load_kv(3, kB, vB);
    compute(kA, vA); load_kv(4, kA, vA);
    compute(kB, vB); load_kv(5, kB, vB);
    compute(kA, vA); load_kv(6, kA, vA);
    compute(kB, vB); load_kv(7, kB, vB);
    compute(kA, vA);
    compute(kB, vB);

    // cross-wave reduction: packed-bf16 partials + per-lane rowsum partials,
    // one barrier; then normalize (full rowsum known) and write bf16 o.
    unsigned* red_o = (unsigned*)smem;               // [4][128 rows][20]
    float* red_l = (float*)(smem + 40960);           // [4][128 rows][4 quads]
    #pragma unroll
    for (int qt2 = 0; qt2 < 2; qt2++)
        #pragma unroll
        for (int qs = 0; qs < 4; qs++) {
            int row = qt2 * 64 + qs * 16 + m16;
            unsigned* rw = red_o + (size_t)(wv * 128 + row) * 20;
            *(uint2*)(rw + 2 * quad) =
                make_uint2(pack_bf16_rtz(oacc[qt2][qs][0][0], oacc[qt2][qs][0][1]),
                           pack_bf16_rtz(oacc[qt2][qs][0][2], oacc[qt2][qs][0][3]));
            *(uint2*)(rw + 8 + 2 * quad) =
                make_uint2(pack_bf16_rtz(oacc[qt2][qs][1][0], oacc[qt2][qs][1][1]),
                           pack_bf16_rtz(oacc[qt2][qs][1][2], oacc[qt2][qs][1][3]));
            red_l[(wv * 128 + row) * 4 + quad] = sacc[qt2][qs];
        }
    __syncthreads();

    // combine 4 waves -> normalized bf16 o[bh][l][d]; 2 threads per q-row
    int q = threadIdx.x >> 1;           // 0..127
    int hcol = threadIdx.x & 1;         // d-half: 0 -> d0..15, 1 -> d16..31
    int s8 = hcol * 8;
    float a16[16];
    #pragma unroll
    for (int i = 0; i < 16; i++) a16[i] = 0.f;
    float ltot = 0.f;
    #pragma unroll
    for (int w = 0; w < 4; w++) {
        const unsigned* rr = red_o + (size_t)(w * 128 + q) * 20 + s8;
        uint4 ua = *(const uint4*)rr;
        uint4 ub = *(const uint4*)(rr + 4);
        a16[0]  += bf_lo(ua.x); a16[1]  += bf_hi(ua.x);
        a16[2]  += bf_lo(ua.y); a16[3]  += bf_hi(ua.y);
        a16[4]  += bf_lo(ua.z); a16[5]  += bf_hi(ua.z);
        a16[6]  += bf_lo(ua.w); a16[7]  += bf_hi(ua.w);
        a16[8]  += bf_lo(ub.x); a16[9]  += bf_hi(ub.x);
        a16[10] += bf_lo(ub.y); a16[11] += bf_hi(ub.y);
        a16[12] += bf_lo(ub.z); a16[13] += bf_hi(ub.z);
        a16[14] += bf_lo(ub.w); a16[15] += bf_hi(ub.w);
        float4 lv = *(const float4*)(red_l + (size_t)(w * 128 + q) * 4);
        ltot += (lv.x + lv.y) + (lv.z + lv.w);
    }
    float inv = 1.0f / ltot;
    uint4 u0, u1;
    u0.x = pack_bf16(a16[0] * inv,  a16[1] * inv);
    u0.y = pack_bf16(a16[2] * inv,  a16[3] * inv);
    u0.z = pack_bf16(a16[4] * inv,  a16[5] * inv);
    u0.w = pack_bf16(a16[6] * inv,  a16[7] * inv);
    u1.x = pack_bf16(a16[8] * inv,  a16[9] * inv);
    u1.y = pack_bf16(a16[10] * inv, a16[11] * inv);
    u1.z = pack_bf16(a16[12] * inv, a16[13] * inv);
    u1.w = pack_bf16(a16[14] * inv, a16[15] * inv);
    unsigned short* op = oo + ((size_t)bh * Lseq + l0 + q) * HD + hcol * 16;
    *(uint4*)op = u0;
    *(uint4*)(op + 8) = u1;
}

// ---------------------------------------------------------------------------
// Kernel 3: projection + bias + residual. o is normalized bf16 in [bh][l][d];
// B-frag loaded directly from global (L2-resident, full-line coalesced).
// Grid 1024: block = 64 o x 32 n. (R4-verified)
// ---------------------------------------------------------------------------
__global__ __launch_bounds__(256) void proj_kernel(const float* __restrict__ wp,
        const unsigned short* __restrict__ oo, const float* __restrict__ bias,
        const float* __restrict__ x, float* __restrict__ out) {
    int bid = blockIdx.x;
    int ot = bid & 1;
    int nt = bid >> 1;                // 0..511, 32-n tiles
    int n0 = nt * 32;
    int t = threadIdx.x;
    int lane = t & 63;
    int wv = t >> 6;
    int m16 = lane & 15, quad = lane >> 4;
    int o0 = ot * 64 + wv * 16;

    bf16x8 af[4];
    #pragma unroll
    for (int ks = 0; ks < 4; ks++) {
        const float* p = wp + (size_t)(o0 + m16) * Cdim + ks * 32 + quad * 8;
        float4 f0 = *(const float4*)p;
        float4 f1 = *(const float4*)(p + 4);
        u32x4 u = {pack_bf16(f0.x, f0.y), pack_bf16(f0.z, f0.w),
                   pack_bf16(f1.x, f1.y), pack_bf16(f1.z, f1.w)};
        af[ks] = __builtin_bit_cast(bf16x8, u);
    }
    float bs[4];
    #pragma unroll
    for (int r = 0; r < 4; r++) bs[r] = bias[o0 + quad * 4 + r];
    int oq = o0 + quad * 4;

    #pragma unroll
    for (int lt2 = 0; lt2 < 2; lt2++) {
        int n = n0 + lt2 * 16 + m16;
        int b = n >> 11, l = n & (Lseq - 1);
        // B-frag straight from global: c = ks*32 + quad*8 + j  ->  h=ks, d=quad*8+j
        bf16x8 bx[4];
        #pragma unroll
        for (int ks = 0; ks < 4; ks++)
            bx[ks] = *(const bf16x8*)(oo + ((size_t)(b * NH + ks) * Lseq + l) * HD + quad * 8);
        f32x4 acc = {0.f, 0.f, 0.f, 0.f};
        #pragma unroll
        for (int ks = 0; ks < 4; ks++) acc = MFMA16(af[ks], bx[ks], acc);
        #pragma unroll
        for (int r = 0; r < 4; r++) {
            size_t xi = ((size_t)b * Cdim + oq + r) * Lseq + l;
            out[xi] = acc[r] + bs[r] + x[xi];
        }
    }
}

extern "C" void kernel_launch(void* const* d_in, const int* in_sizes, int n_in,
                              void* d_out, int out_size, void* d_ws, size_t ws_size,
                              hipStream_t stream) {
    const float* x      = (const float*)d_in[0];
    const float* w_qkv  = (const float*)d_in[1];
    const float* b_qkv  = (const float*)d_in[2];
    const float* w_proj = (const float*)d_in[3];
    const float* b_proj = (const float*)d_in[4];
    float* out = (float*)d_out;

    // ws: qh 4MB | kh 4MB | vh 4MB | oo 4MB bf16 [BH][L][HD] (normalized)
    const size_t E = (size_t)BH * Lseq * HD;   // 2M elems
    unsigned short* qh = (unsigned short*)d_ws;
    unsigned short* kh = qh + E;
    unsigned short* vh = kh + E;
    unsigned short* oo = vh + E;               // [BH][Lseq][HD] bf16, normalized

    qkv_kernel<<<dim3(768), dim3(256), 0, stream>>>(x, w_qkv, b_qkv, qh, kh, vh);
    attn_kernel<<<dim3(512), dim3(256), 0, stream>>>(qh, kh, vh, oo);
    proj_kernel<<<dim3(1024), dim3(256), 0, stream>>>(w_proj, oo, b_proj, x, out);
}